// Round 7
// baseline (380.460 us; speedup 1.0000x reference)
//
#include <hip/hip_runtime.h>
#include <hip/hip_bf16.h>
#include <hip/hip_cooperative_groups.h>
#include <stdint.h>

// B=2, T=2048, D=1024, H=16, hd=64.
// R7: single cooperative mega-kernel (prep -> qkv -> attn -> combine -> outproj
// with grid.sync() between phases) to eliminate ~12us/launch gaps. Phase bodies
// are the verified R5/R6 kernels; outproj2 fusion reverted (134MB refetch bomb).

namespace cg = cooperative_groups;

typedef unsigned short u16;
typedef short bf16x8 __attribute__((ext_vector_type(8)));
typedef float f32x4  __attribute__((ext_vector_type(4)));

#if defined(__has_builtin) && __has_builtin(__builtin_amdgcn_exp2f)
#define EXP2F(x) __builtin_amdgcn_exp2f(x)
#else
#define EXP2F(x) exp2f(x)
#endif

__device__ __forceinline__ u16 f2b(float f) {           // fp32 -> bf16 RNE
  uint32_t u = __float_as_uint(f);
  u += 0x7fffu + ((u >> 16) & 1u);
  return (u16)(u >> 16);
}
__device__ __forceinline__ uint32_t pkbf(float a, float b) {  // v_cvt_pk_bf16_f32
  __hip_bfloat162 h = __float22bfloat162_rn(make_float2(a, b));
  union { __hip_bfloat162 h2; uint32_t u; } cv; cv.h2 = h;
  return cv.u;
}

// async global->LDS DMA, 16B per lane. LDS dest must be uniform-base + lane*16.
__device__ __forceinline__ void gl2lds16(const void* g, void* l) {
  __builtin_amdgcn_global_load_lds(
      (const __attribute__((address_space(1))) unsigned int*)g,
      (__attribute__((address_space(3))) unsigned int*)l, 16, 0, 0);
}

// ------------------------------------------------- 64x64 transpose helper (LDS 9KB)
__device__ __forceinline__ void tr_tile(const void* src, u16* dst, int Kd, int N,
                                        int n0, int k0, int isb, u16* Lt, int tid)
{
  const int r = tid >> 2, cseg = (tid & 3) << 4;
  u16 t[16];
  if (isb) {
    const u16* s = (const u16*)src + (size_t)(k0 + r) * N + n0 + cseg;
    *(uint4*)&t[0] = *(const uint4*)s;
    *(uint4*)&t[8] = *(const uint4*)(s + 8);
  } else {
    const float* s = (const float*)src + (size_t)(k0 + r) * N + n0 + cseg;
    #pragma unroll
    for (int j = 0; j < 4; j++) {
      float4 v = *(const float4*)(s + j * 4);
      t[j*4+0] = f2b(v.x); t[j*4+1] = f2b(v.y); t[j*4+2] = f2b(v.z); t[j*4+3] = f2b(v.w);
    }
  }
  #pragma unroll
  for (int j = 0; j < 16; j++) Lt[(cseg + j) * 72 + r] = t[j];
  __syncthreads();
  const int n = tid >> 2, kseg = (tid & 3) << 4;
  uint4 u0 = *(const uint4*)&Lt[n * 72 + kseg];
  uint4 u1 = *(const uint4*)&Lt[n * 72 + kseg + 8];
  u16* d = dst + (size_t)(n0 + n) * Kd + k0 + kseg;
  *(uint4*)d = u0;
  *(uint4*)(d + 8) = u1;
}

// ------------------------------------------------- qkv 128x128 tile (LDS 32KB)
__device__ __forceinline__ void qkv_tile(
    const u16* __restrict__ Asrc, const u16* __restrict__ Wt,
    const float2* __restrict__ CS,
    u16* __restrict__ Q, u16* __restrict__ K, u16* __restrict__ Vt,
    u16* smem, int n0, int m0, int tid)
{
  u16* As = smem;            // 128*64 u16 = 16KB
  u16* Bs = smem + 8192;     // 16KB
  const int w = tid >> 6, l = tid & 63, lr = l & 15, lq = l >> 4;
  const int mrow0 = (w & 1) * 64;
  const int ncol0 = (w >> 1) * 64;
  const int srow = tid >> 3;
  const int gseg = (tid & 7) ^ (srow & 7);

  f32x4 acc[4][4] = {};

  for (int k0 = 0; k0 < 1024; k0 += 64) {
    __syncthreads();
    #pragma unroll
    for (int rd = 0; rd < 4; rd++) {
      const int row = srow + rd * 32;
      gl2lds16(Asrc + (size_t)(m0 + row) * 1024 + k0 + gseg * 8, &As[tid * 8 + rd * 2048]);
      gl2lds16(Wt + (size_t)(n0 + row) * 1024 + k0 + gseg * 8, &Bs[tid * 8 + rd * 2048]);
    }
    __syncthreads();
    #pragma unroll
    for (int kc = 0; kc < 2; kc++) {
      bf16x8 af[4], bf[4];
      #pragma unroll
      for (int i = 0; i < 4; i++) {
        const int seg = ((kc << 2) | lq) ^ (lr & 7);
        af[i] = *(const bf16x8*)&As[(mrow0 + i * 16 + lr) * 64 + seg * 8];
        bf[i] = *(const bf16x8*)&Bs[(ncol0 + i * 16 + lr) * 64 + seg * 8];
      }
      #pragma unroll
      for (int mb = 0; mb < 4; mb++)
        #pragma unroll
        for (int nb = 0; nb < 4; nb++)
          acc[mb][nb] = __builtin_amdgcn_mfma_f32_16x16x32_bf16(af[mb], bf[nb], acc[mb][nb], 0, 0, 0);
    }
  }

  const int col0 = n0 + ncol0;
  const int sec = col0 >> 10;            // 0=q 1=k 2=v
  const int h = (col0 >> 6) & 15;
  if (sec == 2) {
    #pragma unroll
    for (int mb = 0; mb < 4; mb++) {
      const int row0 = m0 + mrow0 + mb * 16 + lq * 4;
      const int b = row0 >> 11, t0 = row0 & 2047;
      #pragma unroll
      for (int nb = 0; nb < 4; nb++) {
        const int d = nb * 16 + lr;
        uint2 uv;
        uv.x = pkbf(acc[mb][nb][0], acc[mb][nb][1]);
        uv.y = pkbf(acc[mb][nb][2], acc[mb][nb][3]);
        *(uint2*)&Vt[(((size_t)b * 16 + h) * 64 + d) * 2048 + t0] = uv;
      }
    }
  } else {
    u16* dst = (sec == 0) ? Q : K;
    const float qscale = 0.125f * 1.44269504f;   // 1/sqrt(hd) * log2(e), q only
    #pragma unroll
    for (int mb = 0; mb < 4; mb++) {
      const int row0 = m0 + mrow0 + mb * 16 + lq * 4;
      const int b = row0 >> 11, t0 = row0 & 2047;
      #pragma unroll
      for (int nb = 0; nb < 4; nb++) {
        const int d = nb * 16 + lr;
        const int f = d & 31;
        #pragma unroll
        for (int r = 0; r < 4; r++) {
          const int t = t0 + r;
          float2 cs = CS[t * 32 + f];
          float val = acc[mb][nb][r];
          float prt = __shfl_xor(val, 1, 64);   // partner col d^1 = lane lr^1
          float res = fmaf(val, cs.x, ((d & 1) ? prt : -prt) * cs.y);
          if (sec == 0) res *= qscale;
          dst[(((size_t)b * 16 + h) * 2048 + t) * 64 + d] = f2b(res);
        }
      }
    }
  }
}

// ------------------------------------------------- attn tile (LDS 48KB)
__device__ __forceinline__ void attn_tile(
    const u16* __restrict__ Q, const u16* __restrict__ K,
    const u16* __restrict__ Vt, u16* __restrict__ ATT,
    float* __restrict__ Op, float* __restrict__ Ls,
    u16* smem, int bh, int qt, int sh, int ns, int tid)
{
  u16* Ks = smem;               // [2][64*64] = 16KB
  u16* Vs = smem + 8192;        // 16KB
  u16* Ps = smem + 16384;       // [4][32*64] = 16KB
  const int w = tid >> 6, l = tid & 63, lr = l & 15, lq = l >> 4;
  const int slen = 2048 / ns;
  const int sbeg = sh * slen;
  const size_t base = (size_t)bh * (2048 * 64);
  const int qrow0 = qt * 128 + w * 32;
  u16* Psw = Ps + w * (32 * 64);

  __syncthreads();   // guard LDS reuse across grid-stride iterations

  bf16x8 qf[2][2];
  #pragma unroll
  for (int mb = 0; mb < 2; mb++)
    #pragma unroll
    for (int kc = 0; kc < 2; kc++)
      qf[mb][kc] = *(const bf16x8*)(Q + base + (size_t)(qrow0 + mb * 16 + lr) * 64 + kc * 32 + lq * 8);

  f32x4 oa[4][2] = {};            // O^T: [db][mb]
  float2 ls2[2] = {};

  const int srow = tid >> 3;

  auto stage = [&](int buf, int s0) {
    #pragma unroll
    for (int rd = 0; rd < 2; rd++) {
      const int row = srow + rd * 32;
      const int gs = (tid & 7) ^ (row & 7);
      gl2lds16(K + base + (size_t)(s0 + row) * 64 + gs * 8, &Ks[buf * 4096 + tid * 8 + rd * 2048]);
      gl2lds16(Vt + base + (size_t)row * 2048 + s0 + gs * 8, &Vs[buf * 4096 + tid * 8 + rd * 2048]);
    }
  };

  stage(0, sbeg);
  const int nt = slen >> 6;

  #pragma unroll 1
  for (int t = 0; t < nt; t++) {
    const int buf = t & 1;
    __syncthreads();                       // drains DMA for buf, fences prev reads
    if (t + 1 < nt) stage(buf ^ 1, sbeg + (t + 1) * 64);

    bf16x8 kf[4][2], vf[4][2];
    #pragma unroll
    for (int nb = 0; nb < 4; nb++)
      #pragma unroll
      for (int kc = 0; kc < 2; kc++) {
        const int seg = ((kc << 2) | lq) ^ (lr & 7);
        kf[nb][kc] = *(const bf16x8*)&Ks[buf * 4096 + (nb * 16 + lr) * 64 + seg * 8];
        vf[nb][kc] = *(const bf16x8*)&Vs[buf * 4096 + (nb * 16 + lr) * 64 + seg * 8];
      }

    // S^T blocks: row s = sb*16+quad*4+r, col m = mb*16+lane&15
    #pragma unroll
    for (int sb = 0; sb < 4; sb++) {
      #pragma unroll
      for (int mb = 0; mb < 2; mb++) {
        f32x4 st = {};
        st = __builtin_amdgcn_mfma_f32_16x16x32_bf16(kf[sb][0], qf[mb][0], st, 0, 0, 0);
        st = __builtin_amdgcn_mfma_f32_16x16x32_bf16(kf[sb][1], qf[mb][1], st, 0, 0, 0);
        float e0 = EXP2F(st[0]), e1 = EXP2F(st[1]), e2 = EXP2F(st[2]), e3 = EXP2F(st[3]);
        ls2[mb].x += e0 + e2;
        ls2[mb].y += e1 + e3;
        uint2 pp;
        pp.x = pkbf(e0, e1);
        pp.y = pkbf(e2, e3);
        // P[m][s]: s = sb*16+lq*4, 16B-seg XOR swizzle: seg=(2sb+lq/2)^(m&7)
        const int pseg = ((sb << 1) | (lq >> 1)) ^ (lr & 7);
        *(uint2*)&Psw[(mb * 16 + lr) * 64 + pseg * 8 + (lq & 1) * 4] = pp;
      }
    }

    // O^T += V^T · P^T
    #pragma unroll
    for (int mb = 0; mb < 2; mb++) {
      const int rs0 = lq ^ (lr & 7);
      const int rs1 = (4 | lq) ^ (lr & 7);
      bf16x8 pf0 = *(const bf16x8*)&Psw[(mb * 16 + lr) * 64 + rs0 * 8];
      bf16x8 pf1 = *(const bf16x8*)&Psw[(mb * 16 + lr) * 64 + rs1 * 8];
      #pragma unroll
      for (int db = 0; db < 4; db++) {
        oa[db][mb] = __builtin_amdgcn_mfma_f32_16x16x32_bf16(vf[db][0], pf0, oa[db][mb], 0, 0, 0);
        oa[db][mb] = __builtin_amdgcn_mfma_f32_16x16x32_bf16(vf[db][1], pf1, oa[db][mb], 0, 0, 0);
      }
    }
  }

  float lsum[2];
  #pragma unroll
  for (int mb = 0; mb < 2; mb++) {
    float v = ls2[mb].x + ls2[mb].y;
    v += __shfl_xor(v, 16, 64);
    v += __shfl_xor(v, 32, 64);
    lsum[mb] = v;
  }

  const int b = bh >> 4, h = bh & 15;
  if (ns == 1) {
    #pragma unroll
    for (int mb = 0; mb < 2; mb++) {
      const float inv = 1.f / lsum[mb];
      const int t = qrow0 + mb * 16 + lr;
      u16* dst = ATT + ((size_t)(b * 2048 + t)) * 1024 + h * 64;
      #pragma unroll
      for (int db = 0; db < 4; db++) {
        uint2 u;
        u.x = pkbf(oa[db][mb][0] * inv, oa[db][mb][1] * inv);
        u.y = pkbf(oa[db][mb][2] * inv, oa[db][mb][3] * inv);
        *(uint2*)&dst[db * 16 + lq * 4] = u;
      }
    }
  } else {
    float* op = Op + (size_t)sh * (65536ull * 64);
    #pragma unroll
    for (int mb = 0; mb < 2; mb++) {
      const size_t row = (size_t)bh * 2048 + qrow0 + mb * 16 + lr;
      #pragma unroll
      for (int db = 0; db < 4; db++)
        *(f32x4*)&op[row * 64 + db * 16 + lq * 4] = oa[db][mb];
      if (lq == 0) Ls[(size_t)sh * 65536 + row] = lsum[mb];
    }
  }
}

// ------------------------------------------------- outproj 128x128 tile (LDS 32KB)
__device__ __forceinline__ void outproj_tile(
    const u16* __restrict__ A, const u16* __restrict__ Wt,
    int isb, void* __restrict__ outv, u16* smem, int n0, int m0, int tid)
{
  u16* As = smem;
  u16* Bs = smem + 8192;
  const int w = tid >> 6, l = tid & 63, lr = l & 15, lq = l >> 4;
  const int mrow0 = (w & 1) * 64;
  const int ncol0 = (w >> 1) * 64;
  const int srow = tid >> 3;
  const int gseg = (tid & 7) ^ (srow & 7);

  f32x4 acc[4][4] = {};

  for (int k0 = 0; k0 < 1024; k0 += 64) {
    __syncthreads();
    #pragma unroll
    for (int rd = 0; rd < 4; rd++) {
      const int row = srow + rd * 32;
      gl2lds16(A + (size_t)(m0 + row) * 1024 + k0 + gseg * 8, &As[tid * 8 + rd * 2048]);
      gl2lds16(Wt + (size_t)(n0 + row) * 1024 + k0 + gseg * 8, &Bs[tid * 8 + rd * 2048]);
    }
    __syncthreads();
    #pragma unroll
    for (int kc = 0; kc < 2; kc++) {
      bf16x8 af[4], bf[4];
      #pragma unroll
      for (int i = 0; i < 4; i++) {
        const int seg = ((kc << 2) | lq) ^ (lr & 7);
        af[i] = *(const bf16x8*)&As[(mrow0 + i * 16 + lr) * 64 + seg * 8];
        bf[i] = *(const bf16x8*)&Bs[(ncol0 + i * 16 + lr) * 64 + seg * 8];
      }
      #pragma unroll
      for (int mb = 0; mb < 4; mb++)
        #pragma unroll
        for (int nb = 0; nb < 4; nb++)
          acc[mb][nb] = __builtin_amdgcn_mfma_f32_16x16x32_bf16(af[mb], bf[nb], acc[mb][nb], 0, 0, 0);
    }
  }
  #pragma unroll
  for (int mb = 0; mb < 4; mb++) {
    const int row = m0 + mrow0 + mb * 16 + lq * 4;
    #pragma unroll
    for (int nb = 0; nb < 4; nb++) {
      const int col = n0 + ncol0 + nb * 16 + lr;
      #pragma unroll
      for (int r = 0; r < 4; r++) {
        float val = acc[mb][nb][r];
        if (isb) ((u16*)outv)[(size_t)(row + r) * 1024 + col] = f2b(val);
        else     ((float*)outv)[(size_t)(row + r) * 1024 + col] = val;
      }
    }
  }
}

// ------------------------------------------------- mega-kernel
__global__ __launch_bounds__(256, 3) void mega_kernel(
    const void* __restrict__ x, const void* __restrict__ wqkv,
    const void* __restrict__ wout,
    u16* __restrict__ Xb, u16* __restrict__ Wqkvt, u16* __restrict__ Woutt,
    float2* __restrict__ CS, u16* __restrict__ Q, u16* __restrict__ K,
    u16* __restrict__ Vt, u16* __restrict__ ATT,
    float* __restrict__ Op, float* __restrict__ Ls,
    void* __restrict__ outv, int ns)
{
  __shared__ __align__(16) u16 smem[24576];   // 48KB union across phases
  cg::grid_group gg = cg::this_grid();
  const int tid = threadIdx.x;
  const int bid = blockIdx.x;
  const int gsz = gridDim.x;

  // ---- phase 0: per-block dtype sniff (x's first 4096 even u16s)
  int isb;
  {
    int* cnt = (int*)smem;
    if (tid == 0) *cnt = 0;
    __syncthreads();
    int c = 0;
    for (int i = tid; i < 4096; i += 256) {
      float a = fabsf(__uint_as_float(((uint32_t)((const u16*)x)[2 * i]) << 16));
      if (a > 1e-3f && a < 100.f) c++;
    }
    atomicAdd(cnt, c);
    __syncthreads();
    isb = (*cnt > 2048) ? 1 : 0;
  }

  // ---- phase 1: prep (x->bf16 | Wqkv^T | Wout^T | rope table)
  for (int vb = bid; vb < 3328; vb += gsz) {
    __syncthreads();
    if (vb < 2048) {
      if (isb) continue;                  // qkv reads x directly in bf16 mode
      const size_t i = ((size_t)vb * 256 + tid) * 8;
      const float* s = (const float*)x + i;
      float4 a = *(const float4*)s, b = *(const float4*)(s + 4);
      uint4 p;
      p.x = pkbf(a.x, a.y); p.y = pkbf(a.z, a.w);
      p.z = pkbf(b.x, b.y); p.w = pkbf(b.z, b.w);
      *(uint4*)&Xb[i] = p;
    } else if (vb < 2816) {
      const int b = vb - 2048;
      tr_tile(wqkv, Wqkvt, 1024, 3072, (b % 48) * 64, (b / 48) * 64, isb, smem, tid);
    } else if (vb < 3072) {
      const int b = vb - 2816;
      tr_tile(wout, Woutt, 1024, 1024, (b % 16) * 64, (b / 16) * 64, isb, smem, tid);
    } else {
      const int idx = (vb - 3072) * 256 + tid;   // 65536
      const int t = idx >> 5, f = idx & 31;
      float invf = __expf(-(float)f * 0.2878231366242557f);  // ln(1e4)/32
      float th = (float)t * invf;
      float sn, cs;
      sincosf(th, &sn, &cs);
      CS[idx] = make_float2(cs, sn);
    }
  }
  gg.sync();

  // ---- phase 2: qkv GEMM + RoPE (768 tiles of 128x128)
  {
    const u16* Asrc = isb ? (const u16*)x : Xb;
    for (int vb = bid; vb < 768; vb += gsz)
      qkv_tile(Asrc, Wqkvt, CS, Q, K, Vt, smem, (vb % 24) * 128, (vb / 24) * 128, tid);
  }
  gg.sync();

  // ---- phase 3: flash attention (512*ns tiles)
  for (int vb = bid; vb < 512 * ns; vb += gsz) {
    const int r = vb & 511;
    attn_tile(Q, K, Vt, ATT, Op, Ls, smem, r & 31, r >> 5, vb >> 9, ns, tid);
  }
  gg.sync();

  // ---- phase 4: combine s-split partials (ns==2 only)
  if (ns == 2) {
    for (int idx = bid * 256 + tid; idx < 524288; idx += gsz * 256) {
      const int R = idx >> 3;
      const int c = (idx & 7) * 8;
      const float* p0 = Op + (size_t)R * 64 + c;
      const float* p1 = p0 + 65536ull * 64;
      f32x4 a0 = *(const f32x4*)p0, a1 = *(const f32x4*)(p0 + 4);
      f32x4 b0 = *(const f32x4*)p1, b1 = *(const f32x4*)(p1 + 4);
      const float inv = 1.f / (Ls[R] + Ls[65536 + R]);
      const int bh = R >> 11, trow = R & 2047;
      const int b = bh >> 4, h = bh & 15;
      u16* d = ATT + ((size_t)(b * 2048 + trow)) * 1024 + h * 64 + c;
      uint4 u;
      u.x = pkbf((a0[0] + b0[0]) * inv, (a0[1] + b0[1]) * inv);
      u.y = pkbf((a0[2] + b0[2]) * inv, (a0[3] + b0[3]) * inv);
      u.z = pkbf((a1[0] + b1[0]) * inv, (a1[1] + b1[1]) * inv);
      u.w = pkbf((a1[2] + b1[2]) * inv, (a1[3] + b1[3]) * inv);
      *(uint4*)d = u;
    }
  }
  gg.sync();

  // ---- phase 5: output projection (256 tiles of 128x128)
  for (int vb = bid; vb < 256; vb += gsz)
    outproj_tile(ATT, Woutt, isb, outv, smem, (vb & 7) * 128, (vb >> 3) * 128, tid);
}

extern "C" void kernel_launch(void* const* d_in, const int* in_sizes, int n_in,
                              void* d_out, int out_size, void* d_ws, size_t ws_size,
                              hipStream_t stream)
{
  const void* x    = d_in[0];
  const void* wqkv = d_in[1];
  const void* wout = d_in[2];
  char* ws = (char*)d_ws;
  const size_t MB = 1024 * 1024;
  float2* CS     = (float2*)(ws + 1024);            // 512 KB
  u16*    Xb     = (u16*)(ws + 1 * MB);             // 8 MB (aliased by ATT)
  u16*    ATT    = Xb;
  u16*    Wqkvt  = (u16*)(ws + 9 * MB);             // 6 MB
  u16*    Woutt  = (u16*)(ws + 15 * MB);            // 2 MB
  u16*    Q      = (u16*)(ws + 17 * MB);            // 8 MB
  u16*    K      = (u16*)(ws + 25 * MB);            // 8 MB
  u16*    Vt     = (u16*)(ws + 33 * MB);            // 8 MB
  float*  Op     = (float*)(ws + 41 * MB);          // 32 MB (ns=2)
  float*  Ls     = (float*)(ws + 75 * MB);          // 0.5 MB

  int ns = (ws_size >= 76 * MB) ? 2 : 1;            // deterministic across calls

  int nb = 0;
  hipOccupancyMaxActiveBlocksPerMultiprocessor(&nb, mega_kernel, 256, 0);
  if (nb < 1) nb = 1;
  int grid = nb * 256;                              // 256 CUs on MI355X
  if (grid > 768) grid = 768;

  void* outv = d_out;
  void* kargs[] = {
    (void*)&x, (void*)&wqkv, (void*)&wout,
    (void*)&Xb, (void*)&Wqkvt, (void*)&Woutt, (void*)&CS,
    (void*)&Q, (void*)&K, (void*)&Vt, (void*)&ATT,
    (void*)&Op, (void*)&Ls, (void*)&outv, (void*)&ns
  };
  hipLaunchCooperativeKernel((const void*)mega_kernel, dim3(grid), dim3(256),
                             kargs, 0, stream);
}

// Round 9
// 242.454 us; speedup vs baseline: 1.5692x; 1.5692x over previous
//
#include <hip/hip_runtime.h>
#include <hip/hip_bf16.h>
#include <stdint.h>

// B=2, T=2048, D=1024, H=16, hd=64.
// R9 = R8 with the host-pass __has_builtin gate removed (that was the only
// failure). Attention PV uses mfma_f32_16x16x16bf16_1k whose B-layout matches
// S^T's C-layout exactly -> P feeds PV straight from registers (no P LDS
// round-trip). ns=1, 4 launches total.

typedef unsigned short u16;
typedef short bf16x8 __attribute__((ext_vector_type(8)));
typedef short bf16x4 __attribute__((ext_vector_type(4)));
typedef float f32x4  __attribute__((ext_vector_type(4)));

#define EXP2F(x) exp2f(x)   // maps to v_exp_f32 on gfx950 with -O3

#define MFMA16(a, b, c) __builtin_amdgcn_mfma_f32_16x16x16bf16_1k(a, b, c, 0, 0, 0)

__device__ __forceinline__ u16 f2b(float f) {           // fp32 -> bf16 RNE
  uint32_t u = __float_as_uint(f);
  u += 0x7fffu + ((u >> 16) & 1u);
  return (u16)(u >> 16);
}
__device__ __forceinline__ uint32_t pkbf(float a, float b) {  // v_cvt_pk_bf16_f32
  __hip_bfloat162 h = __float22bfloat162_rn(make_float2(a, b));
  union { __hip_bfloat162 h2; uint32_t u; } cv; cv.h2 = h;
  return cv.u;
}

// async global->LDS DMA, 16B per lane. LDS dest must be uniform-base + lane*16.
__device__ __forceinline__ void gl2lds16(const void* g, void* l) {
  __builtin_amdgcn_global_load_lds(
      (const __attribute__((address_space(1))) unsigned int*)g,
      (__attribute__((address_space(3))) unsigned int*)l, 16, 0, 0);
}

// ---------------- per-block dtype sniff (deterministic: all blocks sample the
// same 4096 even u16s of x; bf16 data ~99.9% in [1e-3,100), fp32 halves ~7%).
__device__ __forceinline__ int sniff_local(const u16* x, int* scnt, int tid) {
  if (tid == 0) *scnt = 0;
  __syncthreads();
  int c = 0;
  for (int i = tid; i < 4096; i += 256) {
    float a = fabsf(__uint_as_float(((uint32_t)x[2 * i]) << 16));
    if (a > 1e-3f && a < 100.f) c++;
  }
  atomicAdd(scnt, c);
  __syncthreads();
  return (*scnt > 2048) ? 1 : 0;
}

// ------------------------------------------------- 64x64 transpose helper
__device__ __forceinline__ void tr_tile(const void* src, u16* dst, int Kd, int N,
                                        int n0, int k0, int isb, u16* Lt, int tid)
{
  const int r = tid >> 2, cseg = (tid & 3) << 4;
  u16 t[16];
  if (isb) {
    const u16* s = (const u16*)src + (size_t)(k0 + r) * N + n0 + cseg;
    *(uint4*)&t[0] = *(const uint4*)s;
    *(uint4*)&t[8] = *(const uint4*)(s + 8);
  } else {
    const float* s = (const float*)src + (size_t)(k0 + r) * N + n0 + cseg;
    #pragma unroll
    for (int j = 0; j < 4; j++) {
      float4 v = *(const float4*)(s + j * 4);
      t[j*4+0] = f2b(v.x); t[j*4+1] = f2b(v.y); t[j*4+2] = f2b(v.z); t[j*4+3] = f2b(v.w);
    }
  }
  #pragma unroll
  for (int j = 0; j < 16; j++) Lt[(cseg + j) * 72 + r] = t[j];
  __syncthreads();
  const int n = tid >> 2, kseg = (tid & 3) << 4;
  uint4 u0 = *(const uint4*)&Lt[n * 72 + kseg];
  uint4 u1 = *(const uint4*)&Lt[n * 72 + kseg + 8];
  u16* d = dst + (size_t)(n0 + n) * Kd + k0 + kseg;
  *(uint4*)d = u0;
  *(uint4*)(d + 8) = u1;
}

// ------------------------------------------------- fused prep
// blocks [0,2048): x->bf16 (fp32 input only) ; [2048,2816): Wqkv^T ;
// [2816,3072): Wout^T ; [3072,3328): RoPE table CS[t*32+f] = {cos,sin}
__global__ __launch_bounds__(256) void prep_kernel(
    const void* __restrict__ x, const void* __restrict__ wqkv,
    const void* __restrict__ wout,
    u16* __restrict__ Xb, u16* __restrict__ Wqkvt, u16* __restrict__ Woutt,
    float2* __restrict__ CS)
{
  __shared__ u16 Lt[64 * 72];
  __shared__ int scnt;
  const int bid = blockIdx.x, tid = threadIdx.x;
  const int isb = sniff_local((const u16*)x, &scnt, tid);
  if (bid < 2048) {
    if (isb) return;                    // qkv reads x directly in bf16 mode
    const size_t i = ((size_t)bid * 256 + tid) * 8;
    const float* s = (const float*)x + i;
    float4 a = *(const float4*)s, b = *(const float4*)(s + 4);
    uint4 p;
    p.x = pkbf(a.x, a.y); p.y = pkbf(a.z, a.w);
    p.z = pkbf(b.x, b.y); p.w = pkbf(b.z, b.w);
    *(uint4*)&Xb[i] = p;
  } else if (bid < 2816) {
    const int b = bid - 2048;
    tr_tile(wqkv, Wqkvt, 1024, 3072, (b % 48) * 64, (b / 48) * 64, isb, Lt, tid);
  } else if (bid < 3072) {
    const int b = bid - 2816;
    tr_tile(wout, Woutt, 1024, 1024, (b % 16) * 64, (b / 16) * 64, isb, Lt, tid);
  } else {
    const int idx = (bid - 3072) * 256 + tid;   // 65536
    const int t = idx >> 5, f = idx & 31;
    float invf = __expf(-(float)f * 0.2878231366242557f);  // ln(1e4)/32
    float th = (float)t * invf;
    float sn, cs;
    sincosf(th, &sn, &cs);
    CS[idx] = make_float2(cs, sn);
  }
}

// ------------------------------------------------- QKV GEMM (NT, bf16) + RoPE
__global__ __launch_bounds__(256) void qkv_kernel(
    const void* __restrict__ xraw, const u16* __restrict__ Xb,
    const u16* __restrict__ Wt, const float2* __restrict__ CS,
    u16* __restrict__ Q, u16* __restrict__ K, u16* __restrict__ Vt)
{
  __shared__ u16 As[128 * 64];
  __shared__ u16 Bs[128 * 64];
  __shared__ int scnt;
  const int tid = threadIdx.x;
  const int isb = sniff_local((const u16*)xraw, &scnt, tid);
  const u16* Asrc = isb ? (const u16*)xraw : Xb;   // uniform select
  const int n0 = blockIdx.x * 128;
  const int m0 = blockIdx.y * 128;
  const int w = tid >> 6, l = tid & 63, lr = l & 15, lq = l >> 4;
  const int mrow0 = (w & 1) * 64;
  const int ncol0 = (w >> 1) * 64;
  const int srow = tid >> 3;
  const int gseg = (tid & 7) ^ (srow & 7);

  f32x4 acc[4][4] = {};

  for (int k0 = 0; k0 < 1024; k0 += 64) {
    __syncthreads();
    #pragma unroll
    for (int rd = 0; rd < 4; rd++) {
      const int row = srow + rd * 32;
      gl2lds16(Asrc + (size_t)(m0 + row) * 1024 + k0 + gseg * 8, &As[tid * 8 + rd * 2048]);
      gl2lds16(Wt + (size_t)(n0 + row) * 1024 + k0 + gseg * 8, &Bs[tid * 8 + rd * 2048]);
    }
    __syncthreads();
    #pragma unroll
    for (int kc = 0; kc < 2; kc++) {
      bf16x8 af[4], bf[4];
      #pragma unroll
      for (int i = 0; i < 4; i++) {
        const int seg = ((kc << 2) | lq) ^ (lr & 7);
        af[i] = *(const bf16x8*)&As[(mrow0 + i * 16 + lr) * 64 + seg * 8];
        bf[i] = *(const bf16x8*)&Bs[(ncol0 + i * 16 + lr) * 64 + seg * 8];
      }
      #pragma unroll
      for (int mb = 0; mb < 4; mb++)
        #pragma unroll
        for (int nb = 0; nb < 4; nb++)
          acc[mb][nb] = __builtin_amdgcn_mfma_f32_16x16x32_bf16(af[mb], bf[nb], acc[mb][nb], 0, 0, 0);
    }
  }

  const int col0 = n0 + ncol0;
  const int sec = col0 >> 10;            // 0=q 1=k 2=v
  const int h = (col0 >> 6) & 15;
  if (sec == 2) {
    #pragma unroll
    for (int mb = 0; mb < 4; mb++) {
      const int row0 = m0 + mrow0 + mb * 16 + lq * 4;
      const int b = row0 >> 11, t0 = row0 & 2047;
      #pragma unroll
      for (int nb = 0; nb < 4; nb++) {
        const int d = nb * 16 + lr;
        uint2 uv;
        uv.x = pkbf(acc[mb][nb][0], acc[mb][nb][1]);
        uv.y = pkbf(acc[mb][nb][2], acc[mb][nb][3]);
        *(uint2*)&Vt[(((size_t)b * 16 + h) * 64 + d) * 2048 + t0] = uv;
      }
    }
  } else {
    u16* dst = (sec == 0) ? Q : K;
    const float qscale = 0.125f * 1.44269504f;   // 1/sqrt(hd) * log2(e), q only
    #pragma unroll
    for (int mb = 0; mb < 4; mb++) {
      const int row0 = m0 + mrow0 + mb * 16 + lq * 4;
      const int b = row0 >> 11, t0 = row0 & 2047;
      #pragma unroll
      for (int nb = 0; nb < 4; nb++) {
        const int d = nb * 16 + lr;
        const int f = d & 31;
        #pragma unroll
        for (int r = 0; r < 4; r++) {
          const int t = t0 + r;
          float2 cs = CS[t * 32 + f];
          float val = acc[mb][nb][r];
          float prt = __shfl_xor(val, 1, 64);   // partner col d^1 = lane lr^1
          float res = fmaf(val, cs.x, ((d & 1) ? prt : -prt) * cs.y);
          if (sec == 0) res *= qscale;
          dst[(((size_t)b * 16 + h) * 2048 + t) * 64 + d] = f2b(res);
        }
      }
    }
  }
}

// ------------------------------------------------- MFMA flash attention (R9)
// Block = 4 waves x 32 q-rows = 128 rows of one (b,h). grid 512, 2 blocks/CU.
// S^T = mfma_16x16x32(Kfrag, Qfrag) -> C-layout (col m=lr, row s=lq*4+r) is
// EXACTLY the B-operand layout of mfma_16x16x16 -> exp'd P feeds PV directly
// from registers. V-frags: ds_read_b64 (A-operand k=lq*4+j), swizzle-matched
// to the DMA staging layout. No P LDS at all.
__global__ __launch_bounds__(256, 2) void attn_kernel(
    const u16* __restrict__ Q, const u16* __restrict__ K,
    const u16* __restrict__ Vt, u16* __restrict__ ATT)
{
  __shared__ u16 Ks[2][64 * 64];    // 16 KB
  __shared__ u16 Vs[2][64 * 64];    // 16 KB  (V^T tile: [d][s])
  const int tid = threadIdx.x;
  const int w = tid >> 6, l = tid & 63, lr = l & 15, lq = l >> 4;
  const int bh = blockIdx.x & 31;   // XCD swizzle: same bh -> same XCD L2
  const int qt = blockIdx.x >> 5;   // 0..15
  const size_t base = (size_t)bh * (2048 * 64);
  const int qrow0 = qt * 128 + w * 32;

  // Q fragments (B-operand of 16x16x32: col m = lane&15, k = quad*8+j)
  bf16x8 qf[2][2];
  #pragma unroll
  for (int mb = 0; mb < 2; mb++)
    #pragma unroll
    for (int kc = 0; kc < 2; kc++)
      qf[mb][kc] = *(const bf16x8*)(Q + base + (size_t)(qrow0 + mb * 16 + lr) * 64 + kc * 32 + lq * 8);

  f32x4 oa[4][2] = {};            // O^T: [db][mb]; lane: m=lr, d=db*16+lq*4+reg
  float2 ls2[2] = {};

  const int srow = tid >> 3;

  auto stage = [&](int buf, int s0) {
    #pragma unroll
    for (int rd = 0; rd < 2; rd++) {
      const int row = srow + rd * 32;
      const int gs = (tid & 7) ^ (row & 7);
      gl2lds16(K + base + (size_t)(s0 + row) * 64 + gs * 8, &Ks[buf][tid * 8 + rd * 2048]);
      gl2lds16(Vt + base + (size_t)row * 2048 + s0 + gs * 8, &Vs[buf][tid * 8 + rd * 2048]);
    }
  };

  stage(0, 0);

  #pragma unroll 1
  for (int t = 0; t < 32; t++) {
    const int buf = t & 1;
    __syncthreads();                       // drains DMA for buf, fences prev reads
    if (t + 1 < 32) stage(buf ^ 1, (t + 1) * 64);

    bf16x8 kf[4][2];
    #pragma unroll
    for (int sb = 0; sb < 4; sb++)
      #pragma unroll
      for (int kc = 0; kc < 2; kc++) {
        const int seg = ((kc << 2) | lq) ^ (lr & 7);
        kf[sb][kc] = *(const bf16x8*)&Ks[buf][(sb * 16 + lr) * 64 + seg * 8];
      }

    #pragma unroll
    for (int sb = 0; sb < 4; sb++) {
      // V^T A-frags for this sb: lane (d=db*16+lr, k=s=lq*4+j) -> b64 read.
      // LDS[row][slot] holds global seg slot^(row&7); want s-seg g=(sb<<1)|(lq>>1).
      bf16x4 vf4[4];
      #pragma unroll
      for (int db = 0; db < 4; db++) {
        const int vseg = (((sb << 1) | (lq >> 1)) ^ (lr & 7));
        vf4[db] = *(const bf16x4*)&Vs[buf][(db * 16 + lr) * 64 + vseg * 8 + (lq & 1) * 4];
      }
      #pragma unroll
      for (int mb = 0; mb < 2; mb++) {
        f32x4 st = {};
        st = __builtin_amdgcn_mfma_f32_16x16x32_bf16(kf[sb][0], qf[mb][0], st, 0, 0, 0);
        st = __builtin_amdgcn_mfma_f32_16x16x32_bf16(kf[sb][1], qf[mb][1], st, 0, 0, 0);
        float e0 = EXP2F(st[0]), e1 = EXP2F(st[1]), e2 = EXP2F(st[2]), e3 = EXP2F(st[3]);
        ls2[mb].x += e0 + e2;
        ls2[mb].y += e1 + e3;
        union { uint2 u; bf16x4 v; } pf;
        pf.u.x = pkbf(e0, e1);
        pf.u.y = pkbf(e2, e3);
        #pragma unroll
        for (int db = 0; db < 4; db++)
          oa[db][mb] = MFMA16(vf4[db], pf.v, oa[db][mb]);
      }
    }
  }

  // reduce row sums across quads (lanes lr, lr+16, lr+32, lr+48)
  const int b = bh >> 4, h = bh & 15;
  #pragma unroll
  for (int mb = 0; mb < 2; mb++) {
    float v = ls2[mb].x + ls2[mb].y;
    v += __shfl_xor(v, 16, 64);
    v += __shfl_xor(v, 32, 64);
    const float inv = 1.f / v;
    const int t = qrow0 + mb * 16 + lr;
    u16* dst = ATT + ((size_t)(b * 2048 + t)) * 1024 + h * 64;
    #pragma unroll
    for (int db = 0; db < 4; db++) {
      uint2 u;
      u.x = pkbf(oa[db][mb][0] * inv, oa[db][mb][1] * inv);
      u.y = pkbf(oa[db][mb][2] * inv, oa[db][mb][3] * inv);
      *(uint2*)&dst[db * 16 + lq * 4] = u;
    }
  }
}

// ------------------------------------------------- output projection (NT, bf16)
__global__ __launch_bounds__(256) void outproj_kernel(
    const u16* __restrict__ A, const u16* __restrict__ Wt,
    const void* __restrict__ xraw, void* __restrict__ outv)
{
  __shared__ u16 As[128 * 64];
  __shared__ u16 Bs[128 * 64];
  __shared__ int scnt;
  const int tid = threadIdx.x;
  const int isb = sniff_local((const u16*)xraw, &scnt, tid);
  const int n0 = blockIdx.x * 128;
  const int m0 = blockIdx.y * 128;
  const int w = tid >> 6, l = tid & 63, lr = l & 15, lq = l >> 4;
  const int mrow0 = (w & 1) * 64;
  const int ncol0 = (w >> 1) * 64;
  const int srow = tid >> 3;
  const int gseg = (tid & 7) ^ (srow & 7);

  f32x4 acc[4][4] = {};

  for (int k0 = 0; k0 < 1024; k0 += 64) {
    __syncthreads();
    #pragma unroll
    for (int rd = 0; rd < 4; rd++) {
      const int row = srow + rd * 32;
      gl2lds16(A + (size_t)(m0 + row) * 1024 + k0 + gseg * 8, &As[tid * 8 + rd * 2048]);
      gl2lds16(Wt + (size_t)(n0 + row) * 1024 + k0 + gseg * 8, &Bs[tid * 8 + rd * 2048]);
    }
    __syncthreads();
    #pragma unroll
    for (int kc = 0; kc < 2; kc++) {
      bf16x8 af[4], bf[4];
      #pragma unroll
      for (int i = 0; i < 4; i++) {
        const int seg = ((kc << 2) | lq) ^ (lr & 7);
        af[i] = *(const bf16x8*)&As[(mrow0 + i * 16 + lr) * 64 + seg * 8];
        bf[i] = *(const bf16x8*)&Bs[(ncol0 + i * 16 + lr) * 64 + seg * 8];
      }
      #pragma unroll
      for (int mb = 0; mb < 4; mb++)
        #pragma unroll
        for (int nb = 0; nb < 4; nb++)
          acc[mb][nb] = __builtin_amdgcn_mfma_f32_16x16x32_bf16(af[mb], bf[nb], acc[mb][nb], 0, 0, 0);
    }
  }
  #pragma unroll
  for (int mb = 0; mb < 4; mb++) {
    const int row = m0 + mrow0 + mb * 16 + lq * 4;
    #pragma unroll
    for (int nb = 0; nb < 4; nb++) {
      const int col = n0 + ncol0 + nb * 16 + lr;
      #pragma unroll
      for (int r = 0; r < 4; r++) {
        float val = acc[mb][nb][r];
        if (isb) ((u16*)outv)[(size_t)(row + r) * 1024 + col] = f2b(val);
        else     ((float*)outv)[(size_t)(row + r) * 1024 + col] = val;
      }
    }
  }
}

extern "C" void kernel_launch(void* const* d_in, const int* in_sizes, int n_in,
                              void* d_out, int out_size, void* d_ws, size_t ws_size,
                              hipStream_t stream)
{
  const void* x    = d_in[0];
  const void* wqkv = d_in[1];
  const void* wout = d_in[2];
  char* ws = (char*)d_ws;
  const size_t MB = 1024 * 1024;
  float2* CS     = (float2*)(ws + 1024);            // 512 KB
  u16*    Xb     = (u16*)(ws + 1 * MB);             // 8 MB (aliased by ATT)
  u16*    ATT    = Xb;
  u16*    Wqkvt  = (u16*)(ws + 9 * MB);             // 6 MB
  u16*    Woutt  = (u16*)(ws + 15 * MB);            // 2 MB
  u16*    Q      = (u16*)(ws + 17 * MB);            // 8 MB
  u16*    K      = (u16*)(ws + 25 * MB);            // 8 MB
  u16*    Vt     = (u16*)(ws + 33 * MB);            // 8 MB -> 41 MB total

  prep_kernel<<<3328, 256, 0, stream>>>(x, wqkv, wout, Xb, Wqkvt, Woutt, CS);
  qkv_kernel<<<dim3(24, 32), 256, 0, stream>>>(x, Xb, Wqkvt, CS, Q, K, Vt);
  attn_kernel<<<512, 256, 0, stream>>>(Q, K, Vt, ATT);
  outproj_kernel<<<dim3(8, 32), 256, 0, stream>>>(ATT, Woutt, x, d_out);
}